// Round 7
// baseline (587.682 us; speedup 1.0000x reference)
//
#include <hip/hip_runtime.h>

// LSTM anomaly detector: B=4096, T=512, I=3, H=64 (4H=256 gates)
// R7: two-group software pipeline. Block = 16 batch rows = G0 (even MFMA
// rows) + G1 (odd rows), half a step apart. Each phase a wave issues the
// MFMA chain for one group while running the ACTIVATIONS of the other group
// from g4 accumulators held in registers since the previous phase ->
// matrix pipe and VALU overlap on every SIMD, and preacts never touch LDS.
// A-row m only affects C-row m, so the idle group's rows in the fragment
// are don't-care (mid-write LDS races on them are benign).
// g4 init = +200 makes the t=0 ACT a no-op (all sigmoids -> 0, h -> 0).

#define TLEN 512

typedef float  float4_t __attribute__((ext_vector_type(4)));
typedef __bf16 bf16x8   __attribute__((ext_vector_type(8)));

__device__ __forceinline__ float fexp2(float x){ return __builtin_amdgcn_exp2f(x); }
__device__ __forceinline__ float frcp (float x){ return __builtin_amdgcn_rcpf(x); }

// setup-only: scale then RNE hi/lo split (~2^-17 rel err)
__device__ __forceinline__ void split8s(const float* v, float s, bf16x8& hi, bf16x8& lo){
  #pragma unroll
  for (int j = 0; j < 8; j++){
    const float xx = v[j]*s;
    __bf16 h = (__bf16)xx;
    hi[j] = h;
    lo[j] = (__bf16)(xx - (float)h);
  }
}

#define MFMA(a,b,c) __builtin_amdgcn_mfma_f32_16x16x32_bf16((a),(b),(c),0,0,0)

__global__ __launch_bounds__(256, 1)
void LSTMAnomalyDetector_kernel(
    const float* __restrict__ x,     const float* __restrict__ W_ih,
    const float* __restrict__ W_hh,  const float* __restrict__ b_ih,
    const float* __restrict__ b_hh,  const float* __restrict__ W_dec,
    const float* __restrict__ b_dec, float* __restrict__ out)
{
  __shared__ __align__(16) unsigned short HSH[1152];  // h hi, [16 m][72]
  __shared__ __align__(16) unsigned short HSL[1152];  // h lo
  __shared__ __align__(16) float XP[2*3136];          // x chunks, [16 row][196], parity

  const int tid  = threadIdx.x;
  const int w    = tid >> 6;        // wave 0..3 (owns H-cols w*16..w*16+15 of all gates)
  const int lane = tid & 63;
  const int q    = lane >> 4;
  const int lid  = lane & 15;
  const int b0   = blockIdx.x * 16;
  const int cw   = w*16 + lid;

  // ---- resident weights, activation scales folded in ----
  const float sc[4] = {-1.44269504f, -1.44269504f, 2.88539008f, -1.44269504f};
  bf16x8 Bh[4][2], Bl[4][2];
  bf16x8 Dh[2];
  float  Wi0[4], Wi1[4], Wi2[4], bia[4];

  #pragma unroll
  for (int tl = 0; tl < 4; tl++){
    const int g = tl*64 + cw;                 // gate row of W_hh[256][64]
    #pragma unroll
    for (int kt = 0; kt < 2; kt++){
      const float* p = W_hh + g*64 + kt*32 + q*8;
      float v[8];
      #pragma unroll
      for (int j = 0; j < 8; j++) v[j] = p[j];
      split8s(v, sc[tl], Bh[tl][kt], Bl[tl][kt]);
    }
    Wi0[tl] = W_ih[g*3+0]*sc[tl];
    Wi1[tl] = W_ih[g*3+1]*sc[tl];
    Wi2[tl] = W_ih[g*3+2]*sc[tl];
    bia[tl] = (b_ih[g] + b_hh[g])*sc[tl];
  }
  {
    bf16x8 dummy;
    #pragma unroll
    for (int kt = 0; kt < 2; kt++){
      float v[8] = {0.f,0.f,0.f,0.f,0.f,0.f,0.f,0.f};
      if (lid < 3){
        const float* p = W_dec + lid*64 + kt*32 + q*8;
        #pragma unroll
        for (int j = 0; j < 8; j++) v[j] = p[j];
      }
      split8s(v, 1.0f, Dh[kt], dummy);
    }
  }
  const float bdec = (lid < 3) ? b_dec[lid] : 0.f;

  // ---- zero h (h_{-1}=0 for both groups) ----
  for (int i = tid; i < 576; i += 256){
    ((unsigned int*)HSH)[i] = 0u;
    ((unsigned int*)HSL)[i] = 0u;
  }

  // ---- stage x chunk 0 -> parity 0 ----
  #pragma unroll
  for (int s = 0; s < 3; s++){
    const int f = tid + 256*s; const int row = f/48, off = (f%48)*4;
    *(float4_t*)&XP[row*196 + off] =
        *(const float4_t*)(x + (size_t)(b0+row)*1536 + off);
  }
  __syncthreads();

  // ---- state ----
  float creg[4] = {0.f,0.f,0.f,0.f};   // cs = 2.8854*c; r even = G0, r odd = G1
  bf16x8 ah0, ah1, al0, al1;
  float4_t g4[2][4];                   // held accumulators per group
  float4_t xgA[4], xgB[4];             // C-seeds for next MFMA(G0)/(G1)
  #pragma unroll
  for (int tl = 0; tl < 4; tl++) g4[1][tl] = (float4_t){200.f,200.f,200.f,200.f};

  // lambdas ---------------------------------------------------------------
  auto read_frags = [&](){
    const unsigned short* ph = &HSH[lid*72 + q*8];
    ah0 = *(const bf16x8*)&ph[0]; ah1 = *(const bf16x8*)&ph[32];
    const unsigned short* pl = &HSL[lid*72 + q*8];
    al0 = *(const bf16x8*)&pl[0]; al1 = *(const bf16x8*)&pl[32];
  };
  auto act_store = [&](float4_t* G, int g){
    #pragma unroll
    for (int e = 0; e < 2; e++){
      const int r = g + 2*e;
      const float si = frcp(1.f + fexp2(G[0][r]));
      const float sf = frcp(1.f + fexp2(G[1][r]));
      const float rg = frcp(1.f + fexp2(G[2][r]));
      const float so = frcp(1.f + fexp2(G[3][r]));
      const float ggs = __builtin_fmaf(-5.77078016f, rg, 2.88539008f);
      const float cs  = __builtin_fmaf(sf, creg[r], si*ggs);
      creg[r] = cs;
      const float rc = frcp(1.f + fexp2(cs));
      const float h  = __builtin_fmaf(-2.f, so*rc, so);
      const unsigned u  = __float_as_uint(h);
      const float    lf = h - __uint_as_float(u & 0xFFFF0000u);
      const int m = q*4 + r;
      HSH[m*72 + cw] = (unsigned short)(u >> 16);
      HSL[m*72 + cw] = (unsigned short)(__float_as_uint(lf) >> 16);
    }
  };
  auto compute_xg = [&](float4_t* X, int g, int t){
    const int xb = ((t >> 6) & 1)*3136 + (t & 63)*3;
    #pragma unroll
    for (int tl = 0; tl < 4; tl++) X[tl] = (float4_t){0.f,0.f,0.f,0.f};
    #pragma unroll
    for (int e = 0; e < 2; e++){
      const int r = g + 2*e;
      const float* xp = &XP[xb + (q*4+r)*196];
      const float x0 = xp[0], x1 = xp[1], x2 = xp[2];
      #pragma unroll
      for (int tl = 0; tl < 4; tl++)
        X[tl][r] = __builtin_fmaf(x0, Wi0[tl],
                   __builtin_fmaf(x1, Wi1[tl],
                   __builtin_fmaf(x2, Wi2[tl], bia[tl])));
    }
  };
  auto decode_store = [&](int g, int tout){
    float4_t dA = {bdec, bdec, bdec, bdec};
    float4_t dB = {0.f, 0.f, 0.f, 0.f};
    dA = MFMA(ah0, Dh[0], dA); dA = MFMA(ah1, Dh[1], dA);
    dB = MFMA(al0, Dh[0], dB); dB = MFMA(al1, Dh[1], dB);
    const float4_t d = dA + dB;
    if (lid < 3){
      #pragma unroll
      for (int e = 0; e < 2; e++){
        const int r = g + 2*e;
        out[(size_t)(b0 + q*4 + r)*1536 + tout*3 + lid] = d[r];
      }
    }
  };
  // -----------------------------------------------------------------------

  compute_xg(xgA, 0, 0);   // seed for MFMA(G0, t=0)

  for (int c = 0; c < 8; ++c){
    if (c < 7){
      const int pp = (c+1) & 1;
      #pragma unroll
      for (int s = 0; s < 3; s++){
        const int f = tid + 256*s; const int row = f/48, off = (f%48)*4;
        *(float4_t*)&XP[pp*3136 + row*196 + off] =
            *(const float4_t*)(x + (size_t)(b0+row)*1536 + (c+1)*192 + off);
      }
    }
    const int tbase = c*64;
    for (int dt = 0; dt < 64; ++dt){
      const int t = tbase + dt;

      // ---- phase A: MFMA(G0,t)  ||  ACT(G1,t-1) ----
      read_frags();                       // even rows fresh = h0(t-1)
      act_store(g4[1], 1);                // writes h1(t-1) (t=0: no-op via +200)
      compute_xg(xgB, 1, t);              // seeds for MFMA(G1,t)
      #pragma unroll
      for (int tl = 0; tl < 4; tl++){
        float4_t a = xgA[tl];
        a = MFMA(ah0, Bh[tl][0], a); a = MFMA(ah1, Bh[tl][1], a);
        a = MFMA(al0, Bh[tl][0], a); a = MFMA(al1, Bh[tl][1], a);
        a = MFMA(ah0, Bl[tl][0], a); a = MFMA(ah1, Bl[tl][1], a);
        g4[0][tl] = a;
      }
      if (t && w == (t & 3)) decode_store(0, t-1);
      __syncthreads();

      // ---- phase B: MFMA(G1,t)  ||  ACT(G0,t) ----
      read_frags();                       // odd rows fresh = h1(t-1)
      act_store(g4[0], 0);                // writes h0(t)
      compute_xg(xgA, 0, t+1);            // seeds for MFMA(G0,t+1)
      #pragma unroll
      for (int tl = 0; tl < 4; tl++){
        float4_t a = xgB[tl];
        a = MFMA(ah0, Bh[tl][0], a); a = MFMA(ah1, Bh[tl][1], a);
        a = MFMA(al0, Bh[tl][0], a); a = MFMA(al1, Bh[tl][1], a);
        a = MFMA(ah0, Bl[tl][0], a); a = MFMA(ah1, Bl[tl][1], a);
        g4[1][tl] = a;
      }
      if (t && w == ((t+2) & 3)) decode_store(1, t-1);
      __syncthreads();
    }
  }

  // ---- drain ----
  read_frags();                           // even rows = h0(511)
  if (w == 0) decode_store(0, 511);
  act_store(g4[1], 1);                    // writes h1(511)
  __syncthreads();
  read_frags();                           // odd rows = h1(511)
  if (w == 1) decode_store(1, 511);
}

extern "C" void kernel_launch(void* const* d_in, const int* in_sizes, int n_in,
                              void* d_out, int out_size, void* d_ws, size_t ws_size,
                              hipStream_t stream)
{
  const float* x     = (const float*)d_in[0];
  const float* W_ih  = (const float*)d_in[1];
  const float* W_hh  = (const float*)d_in[2];
  const float* b_ih  = (const float*)d_in[3];
  const float* b_hh  = (const float*)d_in[4];
  const float* W_dec = (const float*)d_in[5];
  const float* b_dec = (const float*)d_in[6];
  float* out = (float*)d_out;

  const int B = in_sizes[0] / (TLEN * 3);   // 4096
  const int blocks = B / 16;                // 256
  hipLaunchKernelGGL(LSTMAnomalyDetector_kernel, dim3(blocks), dim3(256), 0, stream,
                     x, W_ih, W_hh, b_ih, b_hh, W_dec, b_dec, out);
}